// Round 10
// baseline (28.526 us; speedup 1.0000x reference)
//
#include <hip/hip_runtime.h>
#include <math.h>

#define PI_F 3.14159265358979323846f

typedef float f32x4v __attribute__((ext_vector_type(4)));

// ===========================================================================
// Compile-time Pauli engine (verified R9: passed absmax 0.0156).
// Convention: string = i^ph * Prod_u X^{x_u} Z^{z_u}  (X left of Z per wire).
//  - multiply:  ph += 2*popc(a.z & b.x); x^=; z^=
//  - CNOT(c,t) conjugation: x_t ^= x_c; z_c ^= z_t; ph unchanged
// z_w = sum over 3^|S_w| terms: sign * prod g * prod bloch-components.
// ===========================================================================
struct PS { int x, z, ph; };

constexpr int SLEN_[8]      = {3,3,2,2,3,3,4,4};
constexpr int SWIRES_[8][4] = {{2,4,6,0},{3,5,7,0},{0,2,0,0},{1,3,0,0},
                               {0,2,4,0},{1,3,5,0},{0,2,4,6},{1,3,5,7}};
constexpr int NCODE_[8]     = {27,27,9,9,27,27,81,81};
constexpr int NTERMS = 288;

constexpr int cpopc(int v){ int c=0; while(v){ c += v&1; v >>= 1; } return c; }

constexpr PS pmul(PS a, PS b) {
  return PS{ a.x ^ b.x, a.z ^ b.z, (a.ph + b.ph + 2*cpopc(a.z & b.x)) & 3 };
}
constexpr PS pcnot(PS s, int c, int t) {
  PS r = s;
  if ((s.x >> c) & 1) r.x ^= (1 << t);
  if ((s.z >> t) & 1) r.z ^= (1 << c);
  return r;
}
constexpr PS buildTerm(int w, int code) {
  PS s{0,0,0};
  int cc = code;
  for (int i = 0; i < SLEN_[w]; ++i) {
    int v = SWIRES_[w][i];
    int k = cc % 3; cc /= 3;              // 0->X, 1->Y, 2->Z
    PS comp = (k==0) ? PS{1<<v, 0, 0} : (k==1) ? PS{1<<v, 1<<v, 1} : PS{0, 1<<v, 0};
    s = pmul(s, comp);
  }
  for (int i = 7; i >= 0; --i) s = pcnot(s, i, (i+1)&7);   // Ring1 conj
  return s;
}
constexpr int wOf(int t)   { int w=0, acc=0; while (t >= acc + NCODE_[w]) { acc += NCODE_[w]; ++w; } return w; }
constexpr int codeOf(int t){ int w=0, acc=0; while (t >= acc + NCODE_[w]) { acc += NCODE_[w]; ++w; } return t - acc; }
constexpr PS termOf(int t) { return buildTerm(wOf(t), codeOf(t)); }
constexpr float signOf(int t) {
  PS s = termOf(t);
  int e = (s.ph - cpopc(s.x & s.z)) & 3;  // <XZ> = -i<Y>: remove i per Y
  return (e == 0) ? 1.0f : -1.0f;
}

// ---- guaranteed compile-time term evaluation (templates) ------------------
template<int T, int U>
static __device__ __forceinline__ float tfac(const float* bx, const float* by, const float* bz) {
  constexpr PS s = termOf(T);
  constexpr bool xb = (s.x >> U) & 1, zb = (s.z >> U) & 1;
  if constexpr (xb && zb) return by[U];
  else if constexpr (xb)  return bx[U];
  else if constexpr (zb)  return bz[U];
  else                    return 1.0f;
}
template<int T>
static __device__ __forceinline__ float teval(const float* bx, const float* by, const float* bz) {
  return tfac<T,0>(bx,by,bz) * tfac<T,1>(bx,by,bz) * tfac<T,2>(bx,by,bz) * tfac<T,3>(bx,by,bz)
       * tfac<T,4>(bx,by,bz) * tfac<T,5>(bx,by,bz) * tfac<T,6>(bx,by,bz) * tfac<T,7>(bx,by,bz);
}
template<int T>
static __device__ __forceinline__ void evalTerms(const float* __restrict__ cf,
    const float* bx, const float* by, const float* bz, float* zv) {
  if constexpr (T < NTERMS) {
    constexpr int wi = wOf(T);
    zv[wi] = fmaf(cf[T], teval<T>(bx,by,bz), zv[wi]);
    evalTerms<T+1>(cf, bx, by, bz, zv);
  }
}

// ===========================================================================
// Setup: ws layout (floats):
//  [0..31]  U0 params per qubit: u00r,u00i,u01r,u01i (layer-0 Rot)
//  [32..39] Wsum_w   [40..47] 2*Wb_w   [48] bsum   [49] bb
//  [64..127] G[w][w'] = sum_j W[w][j] W[w'][j]
//  [128..415] coeff[t]
// R10: reductions are WAVE-PARALLEL (coalesced loads + shfl_xor butterfly)
// instead of serial per-thread 64-iteration loops (R9's latency bottleneck).
// ===========================================================================
static __device__ __forceinline__ float wredsum(float v) {
#pragma unroll
  for (int m = 1; m < 64; m <<= 1) v += __shfl_xor(v, m, 64);
  return v;
}

__global__ void qbranch_setup(const float* __restrict__ weights,
                              const float* __restrict__ Wm,
                              const float* __restrict__ bias,
                              float* __restrict__ ws)
{
  __shared__ float g[8][3];
  const int tid = threadIdx.x;           // 512 threads = 8 waves
  const int w   = tid >> 6;              // wave id = W row
  const int j   = tid & 63;              // lane = column

  if (tid < 8) {
    // layer-0 Rot matrix entries (reference-validated formulas)
    float phi = weights[tid*3 + 0], th = weights[tid*3 + 1], om = weights[tid*3 + 2];
    float ct = cosf(th*0.5f), st = sinf(th*0.5f);
    float ap = (phi + om)*0.5f, am = (phi - om)*0.5f;
    ws[tid*4+0] =  cosf(ap)*ct;   // u00r
    ws[tid*4+1] = -sinf(ap)*ct;   // u00i
    ws[tid*4+2] = -cosf(am)*st;   // u01r
    ws[tid*4+3] = -sinf(am)*st;   // u01i
    // layer-1 Heisenberg g-vector (FULL angles)
    float phi1 = weights[(8+tid)*3 + 0], th1 = weights[(8+tid)*3 + 1];
    float s1 = sinf(th1), c1 = cosf(th1);
    g[tid][0] = -s1*cosf(phi1);
    g[tid][1] =  s1*sinf(phi1);
    g[tid][2] =  c1;
  }

  // --- wave-parallel reductions (each wave: its W row, coalesced) ---------
  const float rw = Wm[w*64 + j];
  const float bj = bias[j];
  float s;
  s = wredsum(rw);        if (j == 0) ws[32 + w] = s;
  s = wredsum(rw * bj);   if (j == 0) ws[40 + w] = 2.f * s;
  if (w == 0) {
    s = wredsum(bj);      if (j == 0) ws[48] = s;
    s = wredsum(bj * bj); if (j == 0) ws[49] = s;
  }
#pragma unroll
  for (int w2 = 0; w2 < 8; ++w2) {
    s = wredsum(rw * Wm[w2*64 + j]);
    if (j == 0) ws[64 + w*8 + w2] = s;
  }

  __syncthreads();

  // --- 288 weight-dependent coefficients (engine verified R9) -------------
  if (tid < NTERMS) {
    int ww = wOf(tid), code = codeOf(tid);
    float c = signOf(tid);
    int cc = code;
    for (int i = 0; i < SLEN_[ww]; ++i) {
      int k = cc % 3; cc /= 3;
      c *= g[SWIRES_[ww][i]][k];
    }
    ws[128 + tid] = c;
  }
}

// ===========================================================================
// Main: one batch element per LANE (identical to R9).
// ===========================================================================
static __device__ __forceinline__ float rl(float v, int e) {
  return __builtin_bit_cast(float,
    __builtin_amdgcn_readlane(__builtin_bit_cast(int, v), e));
}

__global__ __launch_bounds__(64) void qbranch_main(
    const float* __restrict__ x,     // (B,8)
    const float* __restrict__ ws,    // setup products
    const float* __restrict__ Wm,    // (8,64)
    const float* __restrict__ bias,  // (64)
    const float* __restrict__ gamma, // (64)
    const float* __restrict__ beta,  // (64)
    float* __restrict__ out,         // (B,64)
    int B)
{
  const int lane = threadIdx.x;
  const int base = blockIdx.x * 64;
  const int elem = base + lane;
  const int el   = (elem < B) ? elem : (B - 1);

  // --- per-lane input + Bloch vectors -------------------------------------
  const f32x4v xa = *(const f32x4v*)(x + (size_t)el*8);
  const f32x4v xb_ = *(const f32x4v*)(x + (size_t)el*8 + 4);

  float bx[8], by[8], bz[8];
#pragma unroll
  for (int w = 0; w < 8; ++w) {
    const float xv = (w < 4) ? xa[w] : xb_[w-4];
    const float th = 1.f - 2.f / (__expf(2.f*xv) + 1.f);   // tanh
    const float ha = th * (PI_F * 0.5f);                    // theta/2
    const float c = __cosf(ha), s = __sinf(ha);
    const float u00r = ws[w*4+0], u00i = ws[w*4+1];
    const float u01r = ws[w*4+2], u01i = ws[w*4+3];
    // chi = Rot0 * (c, -i s);  u10=-conj(u01), u11=conj(u00)
    const float x0r =  u00r*c + u01i*s;
    const float x0i =  u00i*c - u01r*s;
    const float x1r = -u01r*c - u00i*s;
    const float x1i =  u01i*c - u00r*s;
    bx[w] = 2.f*(x0r*x1r + x0i*x1i);
    by[w] = 2.f*(x0r*x1i - x0i*x1r);
    bz[w] = x0r*x0r + x0i*x0i - x1r*x1r - x1i*x1i;
  }

  // --- z expectations: 288 compile-time-structured terms ------------------
  float zv[8] = {0.f,0.f,0.f,0.f,0.f,0.f,0.f,0.f};
  evalTerms<0>(ws + 128, bx, by, bz, zv);

  // --- LN stats via precomputed quadratic form ----------------------------
  const float* Wsum = ws + 32;
  const float* Wb2  = ws + 40;
  const float* G    = ws + 64;
  float mu = ws[48];
#pragma unroll
  for (int w = 0; w < 8; ++w) mu = fmaf(zv[w], Wsum[w], mu);
  mu *= (1.f/64.f);
  float q = ws[49];
#pragma unroll
  for (int w = 0; w < 8; ++w) {
    float tw = 0.f;
#pragma unroll
    for (int w2 = 0; w2 < 8; ++w2) tw = fmaf(G[w*8+w2], zv[w2], tw);
    q = fmaf(zv[w], tw, q);
    q = fmaf(zv[w], Wb2[w], q);
  }
  const float var = fmaf(-mu, mu, q * (1.f/64.f));
  const float rs  = rsqrtf(var + 1e-5f);

  // --- projection + LN apply: wave-parallel over outputs, loop elements ---
  const int j = lane;
  const float w0 = Wm[0*64+j], w1 = Wm[1*64+j], w2 = Wm[2*64+j], w3 = Wm[3*64+j];
  const float w4 = Wm[4*64+j], w5 = Wm[5*64+j], w6 = Wm[6*64+j], w7 = Wm[7*64+j];
  const float bj = bias[j], gj = gamma[j], btj = beta[j];

  const int cnt = (B - base < 64) ? (B - base) : 64;
  float* po = out + (size_t)base*64 + j;
#pragma unroll 2
  for (int e = 0; e < cnt; ++e) {
    const float s0 = rl(zv[0], e), s1 = rl(zv[1], e), s2 = rl(zv[2], e), s3 = rl(zv[3], e);
    const float s4 = rl(zv[4], e), s5 = rl(zv[5], e), s6 = rl(zv[6], e), s7 = rl(zv[7], e);
    const float smu = rl(mu, e), srs = rl(rs, e);
    float h = bj;
    h = fmaf(s0, w0, h); h = fmaf(s1, w1, h); h = fmaf(s2, w2, h); h = fmaf(s3, w3, h);
    h = fmaf(s4, w4, h); h = fmaf(s5, w5, h); h = fmaf(s6, w6, h); h = fmaf(s7, w7, h);
    const float o = fmaf((h - smu) * srs, gj, btj);
    *po = o;
    po += 64;
  }
}

// ---------------------------------------------------------------------------
extern "C" void kernel_launch(void* const* d_in, const int* in_sizes, int n_in,
                              void* d_out, int out_size, void* d_ws, size_t ws_size,
                              hipStream_t stream)
{
  const float* x       = (const float*)d_in[0];
  const float* weights = (const float*)d_in[1];
  const float* Wm      = (const float*)d_in[2];
  const float* bias    = (const float*)d_in[3];
  const float* gamma   = (const float*)d_in[4];
  const float* beta    = (const float*)d_in[5];
  float* out = (float*)d_out;
  float* ws  = (float*)d_ws;   // 416 floats used

  const int B = in_sizes[0] / 8;

  hipLaunchKernelGGL(qbranch_setup, dim3(1), dim3(512), 0, stream, weights, Wm, bias, ws);
  hipLaunchKernelGGL(qbranch_main, dim3((B + 63) / 64), dim3(64), 0, stream,
                     x, ws, Wm, bias, gamma, beta, out, B);
}

// Round 11
// 26.713 us; speedup vs baseline: 1.0679x; 1.0679x over previous
//
#include <hip/hip_runtime.h>
#include <math.h>

#define PI_F 3.14159265358979323846f

typedef float f32x4v __attribute__((ext_vector_type(4)));

// ===========================================================================
// Compile-time Pauli engine (verified R9/R10: passed absmax 0.0156).
// string = i^ph * Prod_u X^{x_u} Z^{z_u};
// multiply: ph += 2*popc(a.z & b.x); CNOT(c,t) conj: x_t^=x_c; z_c^=z_t.
// z_w = sum over 3^|S_w| terms: sign * prod g * prod bloch-components.
// ===========================================================================
struct PS { int x, z, ph; };

constexpr int SLEN_[8]      = {3,3,2,2,3,3,4,4};
constexpr int SWIRES_[8][4] = {{2,4,6,0},{3,5,7,0},{0,2,0,0},{1,3,0,0},
                               {0,2,4,0},{1,3,5,0},{0,2,4,6},{1,3,5,7}};
constexpr int NCODE_[8]     = {27,27,9,9,27,27,81,81};
constexpr int NTERMS = 288;

constexpr int cpopc(int v){ int c=0; while(v){ c += v&1; v >>= 1; } return c; }

constexpr PS pmul(PS a, PS b) {
  return PS{ a.x ^ b.x, a.z ^ b.z, (a.ph + b.ph + 2*cpopc(a.z & b.x)) & 3 };
}
constexpr PS pcnot(PS s, int c, int t) {
  PS r = s;
  if ((s.x >> c) & 1) r.x ^= (1 << t);
  if ((s.z >> t) & 1) r.z ^= (1 << c);
  return r;
}
constexpr PS buildTerm(int w, int code) {
  PS s{0,0,0};
  int cc = code;
  for (int i = 0; i < SLEN_[w]; ++i) {
    int v = SWIRES_[w][i];
    int k = cc % 3; cc /= 3;              // 0->X, 1->Y, 2->Z
    PS comp = (k==0) ? PS{1<<v, 0, 0} : (k==1) ? PS{1<<v, 1<<v, 1} : PS{0, 1<<v, 0};
    s = pmul(s, comp);
  }
  for (int i = 7; i >= 0; --i) s = pcnot(s, i, (i+1)&7);   // Ring1 conj
  return s;
}
constexpr int wOf(int t)   { int w=0, acc=0; while (t >= acc + NCODE_[w]) { acc += NCODE_[w]; ++w; } return w; }
constexpr int codeOf(int t){ int w=0, acc=0; while (t >= acc + NCODE_[w]) { acc += NCODE_[w]; ++w; } return t - acc; }
constexpr PS termOf(int t) { return buildTerm(wOf(t), codeOf(t)); }
constexpr float signOf(int t) {
  PS s = termOf(t);
  int e = (s.ph - cpopc(s.x & s.z)) & 3;  // <XZ> = -i<Y>: remove i per Y
  return (e == 0) ? 1.0f : -1.0f;
}

// ---- compile-time term evaluation, register-pressure-fenced ---------------
template<int T, int U>
static __device__ __forceinline__ float tfac(const float* bx, const float* by, const float* bz) {
  constexpr PS s = termOf(T);
  constexpr bool xb = (s.x >> U) & 1, zb = (s.z >> U) & 1;
  if constexpr (xb && zb) return by[U];
  else if constexpr (xb)  return bx[U];
  else if constexpr (zb)  return bz[U];
  else                    return 1.0f;
}
template<int T>
static __device__ __forceinline__ float teval(const float* bx, const float* by, const float* bz) {
  return tfac<T,0>(bx,by,bz) * tfac<T,1>(bx,by,bz) * tfac<T,2>(bx,by,bz) * tfac<T,3>(bx,by,bz)
       * tfac<T,4>(bx,by,bz) * tfac<T,5>(bx,by,bz) * tfac<T,6>(bx,by,bz) * tfac<T,7>(bx,by,bz);
}
template<int T>
static __device__ __forceinline__ void evalTerms(const float* __restrict__ cf,
    const float* bx, const float* by, const float* bz, float* zv) {
  if constexpr (T < NTERMS) {
    if constexpr (T > 0 && (T % 32) == 0)
      __builtin_amdgcn_sched_barrier(0);   // cap coefficient-load hoisting
    constexpr int wi = wOf(T);
    zv[wi] = fmaf(cf[T], teval<T>(bx,by,bz), zv[wi]);
    evalTerms<T+1>(cf, bx, by, bz, zv);
  }
}

// ===========================================================================
// Setup (R10, exonerated): ws layout (floats):
//  [0..31] U0 params; [32..39] Wsum; [40..47] 2*Wb; [48] bsum; [49] bb;
//  [64..127] G[w][w']; [128..415] coeff[t]
// ===========================================================================
static __device__ __forceinline__ float wredsum(float v) {
#pragma unroll
  for (int m = 1; m < 64; m <<= 1) v += __shfl_xor(v, m, 64);
  return v;
}

__global__ void qbranch_setup(const float* __restrict__ weights,
                              const float* __restrict__ Wm,
                              const float* __restrict__ bias,
                              float* __restrict__ ws)
{
  __shared__ float g[8][3];
  const int tid = threadIdx.x;           // 512 threads = 8 waves
  const int w   = tid >> 6;
  const int j   = tid & 63;

  if (tid < 8) {
    float phi = weights[tid*3 + 0], th = weights[tid*3 + 1], om = weights[tid*3 + 2];
    float ct = cosf(th*0.5f), st = sinf(th*0.5f);
    float ap = (phi + om)*0.5f, am = (phi - om)*0.5f;
    ws[tid*4+0] =  cosf(ap)*ct;   // u00r
    ws[tid*4+1] = -sinf(ap)*ct;   // u00i
    ws[tid*4+2] = -cosf(am)*st;   // u01r
    ws[tid*4+3] = -sinf(am)*st;   // u01i
    float phi1 = weights[(8+tid)*3 + 0], th1 = weights[(8+tid)*3 + 1];
    float s1 = sinf(th1), c1 = cosf(th1);
    g[tid][0] = -s1*cosf(phi1);
    g[tid][1] =  s1*sinf(phi1);
    g[tid][2] =  c1;
  }

  const float rw = Wm[w*64 + j];
  const float bj = bias[j];
  float s;
  s = wredsum(rw);        if (j == 0) ws[32 + w] = s;
  s = wredsum(rw * bj);   if (j == 0) ws[40 + w] = 2.f * s;
  if (w == 0) {
    s = wredsum(bj);      if (j == 0) ws[48] = s;
    s = wredsum(bj * bj); if (j == 0) ws[49] = s;
  }
#pragma unroll
  for (int w2 = 0; w2 < 8; ++w2) {
    s = wredsum(rw * Wm[w2*64 + j]);
    if (j == 0) ws[64 + w*8 + w2] = s;
  }

  __syncthreads();

  if (tid < NTERMS) {
    int ww = wOf(tid), code = codeOf(tid);
    float c = signOf(tid);
    int cc = code;
    for (int i = 0; i < SLEN_[ww]; ++i) {
      int k = cc % 3; cc /= 3;
      c *= g[SWIRES_[ww][i]][k];
    }
    ws[128 + tid] = c;
  }
}

// ===========================================================================
// Kernel A — circuit + per-element stats. One element per LANE; NO serial
// projection loop (removed R10->R11). Writes 10 floats/element:
// stats[b*10 + {0..7}] = zv, [8] = mu, [9] = rs.
// ===========================================================================
__global__ __launch_bounds__(64) void qbranch_circuit(
    const float* __restrict__ x,     // (B,8)
    const float* __restrict__ ws,    // setup products
    float* __restrict__ stats,       // (B,10)
    int B)
{
  const int lane = threadIdx.x;
  const int elem = blockIdx.x * 64 + lane;
  const int el   = (elem < B) ? elem : (B - 1);

  const f32x4v xa  = *(const f32x4v*)(x + (size_t)el*8);
  const f32x4v xb_ = *(const f32x4v*)(x + (size_t)el*8 + 4);

  float bx[8], by[8], bz[8];
#pragma unroll
  for (int w = 0; w < 8; ++w) {
    const float xv = (w < 4) ? xa[w] : xb_[w-4];
    const float th = 1.f - 2.f / (__expf(2.f*xv) + 1.f);   // tanh
    const float ha = th * (PI_F * 0.5f);
    const float c = __cosf(ha), s = __sinf(ha);
    const float u00r = ws[w*4+0], u00i = ws[w*4+1];
    const float u01r = ws[w*4+2], u01i = ws[w*4+3];
    const float x0r =  u00r*c + u01i*s;
    const float x0i =  u00i*c - u01r*s;
    const float x1r = -u01r*c - u00i*s;
    const float x1i =  u01i*c - u00r*s;
    bx[w] = 2.f*(x0r*x1r + x0i*x1i);
    by[w] = 2.f*(x0r*x1i - x0i*x1r);
    bz[w] = x0r*x0r + x0i*x0i - x1r*x1r - x1i*x1i;
  }

  float zv[8] = {0.f,0.f,0.f,0.f,0.f,0.f,0.f,0.f};
  evalTerms<0>(ws + 128, bx, by, bz, zv);

  const float* Wsum = ws + 32;
  const float* Wb2  = ws + 40;
  const float* G    = ws + 64;
  float mu = ws[48];
#pragma unroll
  for (int w = 0; w < 8; ++w) mu = fmaf(zv[w], Wsum[w], mu);
  mu *= (1.f/64.f);
  float q = ws[49];
#pragma unroll
  for (int w = 0; w < 8; ++w) {
    float tw = 0.f;
#pragma unroll
    for (int w2 = 0; w2 < 8; ++w2) tw = fmaf(G[w*8+w2], zv[w2], tw);
    q = fmaf(zv[w], tw, q);
    q = fmaf(zv[w], Wb2[w], q);
  }
  const float var = fmaf(-mu, mu, q * (1.f/64.f));
  const float rs  = rsqrtf(var + 1e-5f);

  if (elem < B) {
    float* st = stats + (size_t)elem * 10;
#pragma unroll
    for (int w = 0; w < 8; ++w) st[w] = zv[w];
    st[8] = mu;
    st[9] = rs;
  }
}

// ===========================================================================
// Kernel B — projection + LN apply. Thread (b,j) -> out[b][j].
// 256-thread blocks (4 elements each), fully parallel, memory-bound.
// ===========================================================================
__global__ __launch_bounds__(256) void qbranch_proj(
    const float* __restrict__ stats, // (B,10)
    const float* __restrict__ Wm,    // (8,64)
    const float* __restrict__ bias,  // (64)
    const float* __restrict__ gamma, // (64)
    const float* __restrict__ beta,  // (64)
    float* __restrict__ out,         // (B,64)
    int B)
{
  const int gid = blockIdx.x * 256 + threadIdx.x;
  if (gid >= B * 64) return;
  const int b = gid >> 6;
  const int j = gid & 63;

  const float* st = stats + (size_t)b * 10;
  float h = bias[j];
  h = fmaf(st[0], Wm[0*64+j], h);
  h = fmaf(st[1], Wm[1*64+j], h);
  h = fmaf(st[2], Wm[2*64+j], h);
  h = fmaf(st[3], Wm[3*64+j], h);
  h = fmaf(st[4], Wm[4*64+j], h);
  h = fmaf(st[5], Wm[5*64+j], h);
  h = fmaf(st[6], Wm[6*64+j], h);
  h = fmaf(st[7], Wm[7*64+j], h);
  out[gid] = fmaf((h - st[8]) * st[9], gamma[j], beta[j]);
}

// ---------------------------------------------------------------------------
extern "C" void kernel_launch(void* const* d_in, const int* in_sizes, int n_in,
                              void* d_out, int out_size, void* d_ws, size_t ws_size,
                              hipStream_t stream)
{
  const float* x       = (const float*)d_in[0];
  const float* weights = (const float*)d_in[1];
  const float* Wm      = (const float*)d_in[2];
  const float* bias    = (const float*)d_in[3];
  const float* gamma   = (const float*)d_in[4];
  const float* beta    = (const float*)d_in[5];
  float* out   = (float*)d_out;
  float* ws    = (float*)d_ws;            // [0..415] setup products
  float* stats = (float*)d_ws + 512;      // B*10 floats (640 KiB < ws)

  const int B = in_sizes[0] / 8;

  hipLaunchKernelGGL(qbranch_setup, dim3(1), dim3(512), 0, stream, weights, Wm, bias, ws);
  hipLaunchKernelGGL(qbranch_circuit, dim3((B + 63) / 64), dim3(64), 0, stream,
                     x, ws, stats, B);
  hipLaunchKernelGGL(qbranch_proj, dim3((B * 64 + 255) / 256), dim3(256), 0, stream,
                     stats, Wm, bias, gamma, beta, out, B);
}

// Round 12
// 19.636 us; speedup vs baseline: 1.4527x; 1.3604x over previous
//
#include <hip/hip_runtime.h>
#include <math.h>

#define PI_F 3.14159265358979323846f

typedef float f32x4v __attribute__((ext_vector_type(4)));
typedef int   i32x2  __attribute__((ext_vector_type(2)));

// ===========================================================================
// Compile-time Pauli engine (verified R9-R11, absmax 0.0156).
// ===========================================================================
struct PS { int x, z, ph; };

constexpr int SLEN_[8]      = {3,3,2,2,3,3,4,4};
constexpr int SWIRES_[8][4] = {{2,4,6,0},{3,5,7,0},{0,2,0,0},{1,3,0,0},
                               {0,2,4,0},{1,3,5,0},{0,2,4,6},{1,3,5,7}};
constexpr int NCODE_[8]     = {27,27,9,9,27,27,81,81};
constexpr int NTERMS = 288;

constexpr int cpopc(int v){ int c=0; while(v){ c += v&1; v >>= 1; } return c; }

constexpr PS pmul(PS a, PS b) {
  return PS{ a.x ^ b.x, a.z ^ b.z, (a.ph + b.ph + 2*cpopc(a.z & b.x)) & 3 };
}
constexpr PS pcnot(PS s, int c, int t) {
  PS r = s;
  if ((s.x >> c) & 1) r.x ^= (1 << t);
  if ((s.z >> t) & 1) r.z ^= (1 << c);
  return r;
}
constexpr PS buildTerm(int w, int code) {
  PS s{0,0,0};
  int cc = code;
  for (int i = 0; i < SLEN_[w]; ++i) {
    int v = SWIRES_[w][i];
    int k = cc % 3; cc /= 3;              // 0->X, 1->Y, 2->Z
    PS comp = (k==0) ? PS{1<<v, 0, 0} : (k==1) ? PS{1<<v, 1<<v, 1} : PS{0, 1<<v, 0};
    s = pmul(s, comp);
  }
  for (int i = 7; i >= 0; --i) s = pcnot(s, i, (i+1)&7);   // Ring1 conj
  return s;
}
constexpr int wOf(int t)   { int w=0, acc=0; while (t >= acc + NCODE_[w]) { acc += NCODE_[w]; ++w; } return w; }
constexpr int codeOf(int t){ int w=0, acc=0; while (t >= acc + NCODE_[w]) { acc += NCODE_[w]; ++w; } return t - acc; }
constexpr PS termOf(int t) { return buildTerm(wOf(t), codeOf(t)); }
constexpr float signOf(int t) {
  PS s = termOf(t);
  int e = (s.ph - cpopc(s.x & s.z)) & 3;  // <XZ> = -i<Y>: remove i per Y
  return (e == 0) ? 1.0f : -1.0f;
}

template<int T, int U>
static __device__ __forceinline__ float tfac(const float* bx, const float* by, const float* bz) {
  constexpr PS s = termOf(T);
  constexpr bool xb = (s.x >> U) & 1, zb = (s.z >> U) & 1;
  if constexpr (xb && zb) return by[U];
  else if constexpr (xb)  return bx[U];
  else if constexpr (zb)  return bz[U];
  else                    return 1.0f;
}
template<int T>
static __device__ __forceinline__ float teval(const float* bx, const float* by, const float* bz) {
  return tfac<T,0>(bx,by,bz) * tfac<T,1>(bx,by,bz) * tfac<T,2>(bx,by,bz) * tfac<T,3>(bx,by,bz)
       * tfac<T,4>(bx,by,bz) * tfac<T,5>(bx,by,bz) * tfac<T,6>(bx,by,bz) * tfac<T,7>(bx,by,bz);
}
template<int T, int TEND>
static __device__ __forceinline__ void evalRange(const float* __restrict__ cf,
    const float* bx, const float* by, const float* bz, float* zv) {
  if constexpr (T < TEND) {
    constexpr int wi = wOf(T);
    zv[wi] = fmaf(cf[T], teval<T>(bx,by,bz), zv[wi]);
    evalRange<T+1, TEND>(cf, bx, by, bz, zv);
  }
}

// ===========================================================================
// Cross-lane primitives (verified R5-R8).
// ===========================================================================
template<int CTRL>
static __device__ __forceinline__ float dppf(float v) {
  return __builtin_bit_cast(float,
    __builtin_amdgcn_update_dpp(0, __builtin_bit_cast(int, v), CTRL, 0xF, 0xF, false));
}
static __device__ __forceinline__ float pswap32(float v, int lane) {
  i32x2 r = __builtin_amdgcn_permlane32_swap(
      __builtin_bit_cast(int, v), __builtin_bit_cast(int, v), false, false);
  return __builtin_bit_cast(float, (lane & 32) ? r.x : r.y);
}
static __device__ __forceinline__ float pswap16(float v, int lane) {
  i32x2 r = __builtin_amdgcn_permlane16_swap(
      __builtin_bit_cast(int, v), __builtin_bit_cast(int, v), false, false);
  return __builtin_bit_cast(float, (lane & 16) ? r.x : r.y);
}
template<int MASK>
static __device__ __forceinline__ float lxor(float v, int lane) {
  if constexpr (MASK == 1)       return dppf<0xB1>(v);
  else if constexpr (MASK == 2)  return dppf<0x4E>(v);
  else if constexpr (MASK == 4)  return dppf<0x1B>(dppf<0x141>(v));
  else if constexpr (MASK == 8)  return dppf<0x128>(v);
  else if constexpr (MASK == 16) return pswap16(v, lane);
  else if constexpr (MASK == 32) return pswap32(v, lane);
  else return __shfl_xor(v, MASK, 64);
}
template<int SRC>
static __device__ __forceinline__ float breadl(float v) {
  return __builtin_bit_cast(float,
    __builtin_amdgcn_readlane(__builtin_bit_cast(int, v), SRC));
}

// ===========================================================================
// Setup: ws[0..31] = layer-0 Rot params; ws[128..415] = 288 coefficients.
// ===========================================================================
__global__ void qbranch_setup(const float* __restrict__ weights,
                              float* __restrict__ ws)
{
  __shared__ float g[8][3];
  const int tid = threadIdx.x;
  if (tid < 8) {
    float phi = weights[tid*3 + 0], th = weights[tid*3 + 1], om = weights[tid*3 + 2];
    float ct = cosf(th*0.5f), st = sinf(th*0.5f);
    float ap = (phi + om)*0.5f, am = (phi - om)*0.5f;
    ws[tid*4+0] =  cosf(ap)*ct;   // u00r
    ws[tid*4+1] = -sinf(ap)*ct;   // u00i
    ws[tid*4+2] = -cosf(am)*st;   // u01r
    ws[tid*4+3] = -sinf(am)*st;   // u01i
    float phi1 = weights[(8+tid)*3 + 0], th1 = weights[(8+tid)*3 + 1];
    float s1 = sinf(th1), c1 = cosf(th1);
    g[tid][0] = -s1*cosf(phi1);
    g[tid][1] =  s1*sinf(phi1);
    g[tid][2] =  c1;
  }
  __syncthreads();
  if (tid < NTERMS) {
    int ww = wOf(tid), code = codeOf(tid);
    float c = signOf(tid);
    int cc = code;
    for (int i = 0; i < SLEN_[ww]; ++i) {
      int k = cc % 3; cc /= 3;
      c *= g[SWIRES_[ww][i]][k];
    }
    ws[128 + tid] = c;
  }
}

// ===========================================================================
// Kernel A — circuit. 512-thread block (8 waves) per 64 elements.
// Wave k evaluates term chunk [36k, 36k+36) for all 64 elements (lane=elem).
// Partials combined in LDS; stats = (B,8) zv.
// ===========================================================================
__global__ __launch_bounds__(512) void qbranch_circuit(
    const float* __restrict__ x,     // (B,8)
    const float* __restrict__ ws,    // setup products
    float* __restrict__ stats,       // (B,8)
    int B)
{
  __shared__ float part[8][8][64];   // [wi][chunk][lane]
  const int tid  = threadIdx.x;
  const int k    = tid >> 6;         // wave id = term chunk
  const int lane = tid & 63;
  const int base = blockIdx.x * 64;
  const int elem = base + lane;
  const int el   = (elem < B) ? elem : (B - 1);

  // --- Bloch vectors (each wave recomputes for its 64 elements) -----------
  const f32x4v xa  = *(const f32x4v*)(x + (size_t)el*8);
  const f32x4v xb_ = *(const f32x4v*)(x + (size_t)el*8 + 4);

  float bx[8], by[8], bz[8];
#pragma unroll
  for (int w = 0; w < 8; ++w) {
    const float xv = (w < 4) ? xa[w] : xb_[w-4];
    const float th = 1.f - 2.f / (__expf(2.f*xv) + 1.f);   // tanh
    const float ha = th * (PI_F * 0.5f);
    const float c = __cosf(ha), s = __sinf(ha);
    const float u00r = ws[w*4+0], u00i = ws[w*4+1];
    const float u01r = ws[w*4+2], u01i = ws[w*4+3];
    const float x0r =  u00r*c + u01i*s;
    const float x0i =  u00i*c - u01r*s;
    const float x1r = -u01r*c - u00i*s;
    const float x1i =  u01i*c - u00r*s;
    bx[w] = 2.f*(x0r*x1r + x0i*x1i);
    by[w] = 2.f*(x0r*x1i - x0i*x1r);
    bz[w] = x0r*x0r + x0i*x0i - x1r*x1r - x1i*x1i;
  }

  // --- this wave's 36-term chunk (wave-uniform branch) --------------------
  float zv[8] = {0.f,0.f,0.f,0.f,0.f,0.f,0.f,0.f};
  const float* cf = ws + 128;
  switch (k) {
    case 0: evalRange<  0,  36>(cf, bx, by, bz, zv); break;
    case 1: evalRange< 36,  72>(cf, bx, by, bz, zv); break;
    case 2: evalRange< 72, 108>(cf, bx, by, bz, zv); break;
    case 3: evalRange<108, 144>(cf, bx, by, bz, zv); break;
    case 4: evalRange<144, 180>(cf, bx, by, bz, zv); break;
    case 5: evalRange<180, 216>(cf, bx, by, bz, zv); break;
    case 6: evalRange<216, 252>(cf, bx, by, bz, zv); break;
    case 7: evalRange<252, 288>(cf, bx, by, bz, zv); break;
  }

#pragma unroll
  for (int wi = 0; wi < 8; ++wi) part[wi][k][lane] = zv[wi];
  __syncthreads();

  // --- combine: thread t -> (elem l = t>>3, wi = t&7); coalesced store ----
  const int lr = tid >> 3;
  const int wi = tid & 7;
  float s = 0.f;
#pragma unroll
  for (int kk = 0; kk < 8; ++kk) s += part[wi][kk][lr];
  if (base + lr < B) stats[(size_t)(base + lr)*8 + wi] = s;
}

// ===========================================================================
// Kernel B — projection + LN. One WAVE per element (lane j = output col).
// ===========================================================================
__global__ __launch_bounds__(256) void qbranch_proj(
    const float* __restrict__ stats, // (B,8)
    const float* __restrict__ Wm,    // (8,64)
    const float* __restrict__ bias,  // (64)
    const float* __restrict__ gamma, // (64)
    const float* __restrict__ beta,  // (64)
    float* __restrict__ out,         // (B,64)
    int B)
{
  const int lane = threadIdx.x & 63;
  const int b    = blockIdx.x * 4 + (threadIdx.x >> 6);
  if (b >= B) return;
  const int j = lane;

  const float* st = stats + (size_t)b * 8;   // wave-uniform -> scalar loads
  float h = bias[j];
  h = fmaf(st[0], Wm[0*64+j], h);
  h = fmaf(st[1], Wm[1*64+j], h);
  h = fmaf(st[2], Wm[2*64+j], h);
  h = fmaf(st[3], Wm[3*64+j], h);
  h = fmaf(st[4], Wm[4*64+j], h);
  h = fmaf(st[5], Wm[5*64+j], h);
  h = fmaf(st[6], Wm[6*64+j], h);
  h = fmaf(st[7], Wm[7*64+j], h);

  // fused sum/sumsq butterfly (verified R6-R8)
  const bool lb0 = (lane & 1) != 0;
  float S = h, Q = h*h;
  float snd = lb0 ? S : Q;
  float acc = (lb0 ? Q : S) + lxor<1>(snd, lane);
  acc += lxor< 2>(acc, lane);
  acc += lxor< 4>(acc, lane);
  acc += lxor< 8>(acc, lane);
  acc += lxor<16>(acc, lane);
  acc += lxor<32>(acc, lane);
  const float Ssum = breadl<0>(acc);
  const float Qsum = breadl<1>(acc);
  const float mu  = Ssum * (1.f/64.f);
  const float var = fmaf(-mu, mu, Qsum * (1.f/64.f));

  out[(size_t)b*64 + j] = fmaf((h - mu) * rsqrtf(var + 1e-5f), gamma[j], beta[j]);
}

// ---------------------------------------------------------------------------
extern "C" void kernel_launch(void* const* d_in, const int* in_sizes, int n_in,
                              void* d_out, int out_size, void* d_ws, size_t ws_size,
                              hipStream_t stream)
{
  const float* x       = (const float*)d_in[0];
  const float* weights = (const float*)d_in[1];
  const float* Wm      = (const float*)d_in[2];
  const float* bias    = (const float*)d_in[3];
  const float* gamma   = (const float*)d_in[4];
  const float* beta    = (const float*)d_in[5];
  float* out   = (float*)d_out;
  float* ws    = (float*)d_ws;            // [0..415] setup products
  float* stats = (float*)d_ws + 512;      // B*8 floats

  const int B = in_sizes[0] / 8;

  hipLaunchKernelGGL(qbranch_setup, dim3(1), dim3(512), 0, stream, weights, ws);
  hipLaunchKernelGGL(qbranch_circuit, dim3((B + 63) / 64), dim3(512), 0, stream,
                     x, ws, stats, B);
  hipLaunchKernelGGL(qbranch_proj, dim3((B + 3) / 4), dim3(256), 0, stream,
                     stats, Wm, bias, gamma, beta, out, B);
}

// Round 13
// 15.903 us; speedup vs baseline: 1.7938x; 1.2348x over previous
//
#include <hip/hip_runtime.h>
#include <math.h>

#define PI_F 3.14159265358979323846f

typedef float f32x4v __attribute__((ext_vector_type(4)));
typedef int   i32x2  __attribute__((ext_vector_type(2)));

// ===========================================================================
// Compile-time Pauli engine (verified R9-R12, absmax 0.0156).
// ===========================================================================
struct PS { int x, z, ph; };

constexpr int SLEN_[8]      = {3,3,2,2,3,3,4,4};
constexpr int SWIRES_[8][4] = {{2,4,6,0},{3,5,7,0},{0,2,0,0},{1,3,0,0},
                               {0,2,4,0},{1,3,5,0},{0,2,4,6},{1,3,5,7}};
constexpr int NCODE_[8]     = {27,27,9,9,27,27,81,81};
constexpr int NTERMS = 288;

constexpr int cpopc(int v){ int c=0; while(v){ c += v&1; v >>= 1; } return c; }

constexpr PS pmul(PS a, PS b) {
  return PS{ a.x ^ b.x, a.z ^ b.z, (a.ph + b.ph + 2*cpopc(a.z & b.x)) & 3 };
}
constexpr PS pcnot(PS s, int c, int t) {
  PS r = s;
  if ((s.x >> c) & 1) r.x ^= (1 << t);
  if ((s.z >> t) & 1) r.z ^= (1 << c);
  return r;
}
constexpr PS buildTerm(int w, int code) {
  PS s{0,0,0};
  int cc = code;
  for (int i = 0; i < SLEN_[w]; ++i) {
    int v = SWIRES_[w][i];
    int k = cc % 3; cc /= 3;              // 0->X, 1->Y, 2->Z
    PS comp = (k==0) ? PS{1<<v, 0, 0} : (k==1) ? PS{1<<v, 1<<v, 1} : PS{0, 1<<v, 0};
    s = pmul(s, comp);
  }
  for (int i = 7; i >= 0; --i) s = pcnot(s, i, (i+1)&7);   // Ring1 conj
  return s;
}
constexpr int wOf(int t)   { int w=0, acc=0; while (t >= acc + NCODE_[w]) { acc += NCODE_[w]; ++w; } return w; }
constexpr int codeOf(int t){ int w=0, acc=0; while (t >= acc + NCODE_[w]) { acc += NCODE_[w]; ++w; } return t - acc; }
constexpr PS termOf(int t) { return buildTerm(wOf(t), codeOf(t)); }
constexpr float signOf(int t) {
  PS s = termOf(t);
  int e = (s.ph - cpopc(s.x & s.z)) & 3;  // <XZ> = -i<Y>: remove i per Y
  return (e == 0) ? 1.0f : -1.0f;
}

template<int T, int U>
static __device__ __forceinline__ float tfac(const float* bx, const float* by, const float* bz) {
  constexpr PS s = termOf(T);
  constexpr bool xb = (s.x >> U) & 1, zb = (s.z >> U) & 1;
  if constexpr (xb && zb) return by[U];
  else if constexpr (xb)  return bx[U];
  else if constexpr (zb)  return bz[U];
  else                    return 1.0f;
}
template<int T>
static __device__ __forceinline__ float teval(const float* bx, const float* by, const float* bz) {
  return tfac<T,0>(bx,by,bz) * tfac<T,1>(bx,by,bz) * tfac<T,2>(bx,by,bz) * tfac<T,3>(bx,by,bz)
       * tfac<T,4>(bx,by,bz) * tfac<T,5>(bx,by,bz) * tfac<T,6>(bx,by,bz) * tfac<T,7>(bx,by,bz);
}
template<int T, int TEND>
static __device__ __forceinline__ void evalRange(const float* __restrict__ cf,
    const float* bx, const float* by, const float* bz, float* zv) {
  if constexpr (T < TEND) {
    constexpr int wi = wOf(T);
    zv[wi] = fmaf(cf[T], teval<T>(bx,by,bz), zv[wi]);
    evalRange<T+1, TEND>(cf, bx, by, bz, zv);
  }
}

// ===========================================================================
// Cross-lane primitives (verified R5-R12).
// ===========================================================================
template<int CTRL>
static __device__ __forceinline__ float dppf(float v) {
  return __builtin_bit_cast(float,
    __builtin_amdgcn_update_dpp(0, __builtin_bit_cast(int, v), CTRL, 0xF, 0xF, false));
}
static __device__ __forceinline__ float pswap32(float v, int lane) {
  i32x2 r = __builtin_amdgcn_permlane32_swap(
      __builtin_bit_cast(int, v), __builtin_bit_cast(int, v), false, false);
  return __builtin_bit_cast(float, (lane & 32) ? r.x : r.y);
}
static __device__ __forceinline__ float pswap16(float v, int lane) {
  i32x2 r = __builtin_amdgcn_permlane16_swap(
      __builtin_bit_cast(int, v), __builtin_bit_cast(int, v), false, false);
  return __builtin_bit_cast(float, (lane & 16) ? r.x : r.y);
}
template<int MASK>
static __device__ __forceinline__ float lxor(float v, int lane) {
  if constexpr (MASK == 1)       return dppf<0xB1>(v);
  else if constexpr (MASK == 2)  return dppf<0x4E>(v);
  else if constexpr (MASK == 4)  return dppf<0x1B>(dppf<0x141>(v));
  else if constexpr (MASK == 8)  return dppf<0x128>(v);
  else if constexpr (MASK == 16) return pswap16(v, lane);
  else if constexpr (MASK == 32) return pswap32(v, lane);
  else return __shfl_xor(v, MASK, 64);
}
template<int SRC>
static __device__ __forceinline__ float breadl(float v) {
  return __builtin_bit_cast(float,
    __builtin_amdgcn_readlane(__builtin_bit_cast(int, v), SRC));
}

// ===========================================================================
// SINGLE fused kernel. 512-thread block (8 waves) per 64 elements.
//  Phase 0: block-redundant setup (trig + 288 coefficients) -> LDS
//  Phase 1: wave k evaluates term chunk [36k,36k+36) for 64 elems (lane=elem)
//  Phase 2: combine partials -> zvc[64][8]
//  Phase 3: wave k projects+LNs elements [8k,8k+8) (lane = output col)
// ===========================================================================
__global__ __launch_bounds__(512) void qbranch_fused(
    const float* __restrict__ x,       // (B,8)
    const float* __restrict__ weights, // (2,8,3)
    const float* __restrict__ Wm,      // (8,64)
    const float* __restrict__ bias,    // (64)
    const float* __restrict__ gamma,   // (64)
    const float* __restrict__ beta,    // (64)
    float* __restrict__ out,           // (B,64)
    int B)
{
  __shared__ float u0s[8][4];        // layer-0 Rot params
  __shared__ float gsh[8][3];        // layer-1 Heisenberg g-vectors
  __shared__ float cf[NTERMS];       // 288 coefficients
  __shared__ float part[8][8][64];   // [wi][chunk][lane]  (16 KB)
  __shared__ float zvc[64][8];       // combined zv per element

  const int tid  = threadIdx.x;
  const int k    = tid >> 6;         // wave id
  const int lane = tid & 63;
  const int base = blockIdx.x * 64;

  // --- Phase 0: block-redundant setup -------------------------------------
  if (tid < 8) {
    float phi = weights[tid*3 + 0], th = weights[tid*3 + 1], om = weights[tid*3 + 2];
    float ct = cosf(th*0.5f), st = sinf(th*0.5f);
    float ap = (phi + om)*0.5f, am = (phi - om)*0.5f;
    u0s[tid][0] =  cosf(ap)*ct;   // u00r
    u0s[tid][1] = -sinf(ap)*ct;   // u00i
    u0s[tid][2] = -cosf(am)*st;   // u01r
    u0s[tid][3] = -sinf(am)*st;   // u01i
    float phi1 = weights[(8+tid)*3 + 0], th1 = weights[(8+tid)*3 + 1];
    float s1 = sinf(th1), c1 = cosf(th1);
    gsh[tid][0] = -s1*cosf(phi1);
    gsh[tid][1] =  s1*sinf(phi1);
    gsh[tid][2] =  c1;
  }
  __syncthreads();
  if (tid < NTERMS) {
    int ww = wOf(tid), code = codeOf(tid);
    float c = signOf(tid);
    int cc = code;
    for (int i = 0; i < SLEN_[ww]; ++i) {
      int kk = cc % 3; cc /= 3;
      c *= gsh[SWIRES_[ww][i]][kk];
    }
    cf[tid] = c;
  }
  __syncthreads();

  // --- Phase 1: Bloch vectors + this wave's 36-term chunk -----------------
  const int elem = base + lane;
  const int el   = (elem < B) ? elem : (B - 1);
  const f32x4v xa  = *(const f32x4v*)(x + (size_t)el*8);
  const f32x4v xb_ = *(const f32x4v*)(x + (size_t)el*8 + 4);

  float bx[8], by[8], bz[8];
#pragma unroll
  for (int w = 0; w < 8; ++w) {
    const float xv = (w < 4) ? xa[w] : xb_[w-4];
    const float th = 1.f - 2.f / (__expf(2.f*xv) + 1.f);   // tanh
    const float ha = th * (PI_F * 0.5f);
    const float c = __cosf(ha), s = __sinf(ha);
    const float u00r = u0s[w][0], u00i = u0s[w][1];
    const float u01r = u0s[w][2], u01i = u0s[w][3];
    const float x0r =  u00r*c + u01i*s;
    const float x0i =  u00i*c - u01r*s;
    const float x1r = -u01r*c - u00i*s;
    const float x1i =  u01i*c - u00r*s;
    bx[w] = 2.f*(x0r*x1r + x0i*x1i);
    by[w] = 2.f*(x0r*x1i - x0i*x1r);
    bz[w] = x0r*x0r + x0i*x0i - x1r*x1r - x1i*x1i;
  }

  float zv[8] = {0.f,0.f,0.f,0.f,0.f,0.f,0.f,0.f};
  switch (k) {
    case 0: evalRange<  0,  36>(cf, bx, by, bz, zv); break;
    case 1: evalRange< 36,  72>(cf, bx, by, bz, zv); break;
    case 2: evalRange< 72, 108>(cf, bx, by, bz, zv); break;
    case 3: evalRange<108, 144>(cf, bx, by, bz, zv); break;
    case 4: evalRange<144, 180>(cf, bx, by, bz, zv); break;
    case 5: evalRange<180, 216>(cf, bx, by, bz, zv); break;
    case 6: evalRange<216, 252>(cf, bx, by, bz, zv); break;
    case 7: evalRange<252, 288>(cf, bx, by, bz, zv); break;
  }
#pragma unroll
  for (int wi = 0; wi < 8; ++wi) part[wi][k][lane] = zv[wi];
  __syncthreads();

  // --- Phase 2: combine -> zvc[elem][wi] ----------------------------------
  {
    const int lr = tid >> 3;
    const int wi = tid & 7;
    float s = 0.f;
#pragma unroll
    for (int kk = 0; kk < 8; ++kk) s += part[wi][kk][lr];
    zvc[lr][wi] = s;
  }
  __syncthreads();

  // --- Phase 3: projection + LN. Wave k handles elements [8k, 8k+8) -------
  const int j = lane;
  const float w0 = Wm[0*64+j], w1 = Wm[1*64+j], w2 = Wm[2*64+j], w3 = Wm[3*64+j];
  const float w4 = Wm[4*64+j], w5 = Wm[5*64+j], w6 = Wm[6*64+j], w7 = Wm[7*64+j];
  const float bj = bias[j], gj = gamma[j], btj = beta[j];
  const bool lb0 = (lane & 1) != 0;

#pragma unroll
  for (int e = 0; e < 8; ++e) {
    const int l = k*8 + e;
    if (base + l >= B) break;
    const float s0 = zvc[l][0], s1 = zvc[l][1], s2 = zvc[l][2], s3 = zvc[l][3];
    const float s4 = zvc[l][4], s5 = zvc[l][5], s6 = zvc[l][6], s7 = zvc[l][7];
    float h = bj;
    h = fmaf(s0, w0, h); h = fmaf(s1, w1, h); h = fmaf(s2, w2, h); h = fmaf(s3, w3, h);
    h = fmaf(s4, w4, h); h = fmaf(s5, w5, h); h = fmaf(s6, w6, h); h = fmaf(s7, w7, h);

    float S = h, Q = h*h;
    float snd = lb0 ? S : Q;
    float acc = (lb0 ? Q : S) + lxor<1>(snd, lane);
    acc += lxor< 2>(acc, lane);
    acc += lxor< 4>(acc, lane);
    acc += lxor< 8>(acc, lane);
    acc += lxor<16>(acc, lane);
    acc += lxor<32>(acc, lane);
    const float Ssum = breadl<0>(acc);
    const float Qsum = breadl<1>(acc);
    const float mu  = Ssum * (1.f/64.f);
    const float var = fmaf(-mu, mu, Qsum * (1.f/64.f));

    out[(size_t)(base + l)*64 + j] =
        fmaf((h - mu) * rsqrtf(var + 1e-5f), gj, btj);
  }
}

// ---------------------------------------------------------------------------
extern "C" void kernel_launch(void* const* d_in, const int* in_sizes, int n_in,
                              void* d_out, int out_size, void* d_ws, size_t ws_size,
                              hipStream_t stream)
{
  const float* x       = (const float*)d_in[0];
  const float* weights = (const float*)d_in[1];
  const float* Wm      = (const float*)d_in[2];
  const float* bias    = (const float*)d_in[3];
  const float* gamma   = (const float*)d_in[4];
  const float* beta    = (const float*)d_in[5];
  float* out = (float*)d_out;

  const int B = in_sizes[0] / 8;

  hipLaunchKernelGGL(qbranch_fused, dim3((B + 63) / 64), dim3(512), 0, stream,
                     x, weights, Wm, bias, gamma, beta, out, B);
}